// Round 14
// baseline (4275.664 us; speedup 1.0000x reference)
//
#include <hip/hip_runtime.h>
#include <hip/hip_bf16.h>
#include <stdint.h>

// ---------------------------------------------------------------------------
// Peephole LSTM, SEQ=512, B=64, I=H=1024.  Persistent-kernel, 256 blocks.
// Round-23: R21 base (verified 4.11ms) + 4x PAYLOAD/FLAG REPLICATION.
//  * R22 post-mortem: hoisted probes regressed (chain is tight; probes
//    always stale).  Reverted to R21 wholesale.
//  * Pull-leg arithmetic: 64 blocks/group read the SAME 512 lines per leg
//    -> 64x fan-out serialization at L3 slices ~ 2us/leg (matches R12's
//    measured burst cost).  Fix: producers write tiles + flags to 4
//    REPLICAS; consumer cg reads replica cg&3.  Line multiplicity 64->16
//    on payload pulls AND flag polls.
//  * Replicas live in the WA tail [23068672,25165824) — DEAD after weight
//    pinning (R21).  One-time grid ready-barrier after pinning protects
//    cg58-63 weights from any step-0 replica store.  h0 initial replicas
//    prep-written to the old hbf region (INIT_H); t==0 pulls read there.
//  * Ordering: per-wave drain covers all 4 replica stores before the 4
//    flag bumps (R12 discipline).  WAR: same 2-slot ring per replica;
//    R19/R21 collective-c-wait closure covers every replica.
//  * Everything else byte-identical to R21 (verified).
// ---------------------------------------------------------------------------

typedef __attribute__((ext_vector_type(8))) short short8;
typedef __attribute__((ext_vector_type(4))) float f32x4;
typedef __attribute__((ext_vector_type(4))) unsigned int uint4v;

#define OFF_WB   25165824u   // WA: 64cg*4g*96kc*64l*8e bf16
#define REP_H    23068672u   // h replicas: (r*2+slot)*131072, in WA tail
#define REP_C    24117248u   // c replicas: same layout
#define INIT_H   27262976u   // h0 initial, 4 replicas x 131072 (prep-written)
#define OFF_BAR  27787264u   // hflag r*4096+(grp*64+cg)*16; cflag +16384 dw
#define WS_NEED  27918336u   // ready counter = bar[15] (unused flag dword)

__device__ __forceinline__ short bfc(float f) {
  __hip_bfloat16 h = __float2bfloat16(f);
  return *reinterpret_cast<short*>(&h);
}
__device__ __forceinline__ unsigned pk2(float a, float b) {
  __hip_bfloat16 ha = __float2bfloat16(a), hb = __float2bfloat16(b);
  unsigned short ua = *reinterpret_cast<unsigned short*>(&ha);
  unsigned short ub = *reinterpret_cast<unsigned short*>(&hb);
  return (unsigned)ua | ((unsigned)ub << 16);
}
__device__ __forceinline__ float sig_fast(float v) {
  return __fdividef(1.f, 1.f + __expf(-v));
}
__device__ __forceinline__ float tanh_fast(float v) {
  float a = fabsf(v);
  float e = __expf(-2.f * a);
  float t = (1.f - e) * __fdividef(1.f, 1.f + e);
  return copysignf(t, v);
}

// ---- L1+L2-bypassing accesses (coherent at L3 across XCDs) ----
__device__ __forceinline__ uint4v ldg_sc(const void* p) {
  uint4v r;
  asm volatile("global_load_dwordx4 %0, %1, off sc0 sc1" : "=v"(r) : "v"(p));
  return r;
}
__device__ __forceinline__ unsigned poll_sc(const unsigned* p) {
  unsigned r;
  asm volatile("global_load_dword %0, %1, off sc0 sc1\n\ts_waitcnt vmcnt(0)"
               : "=v"(r) : "v"(p) : "memory");
  return r;
}
__device__ __forceinline__ void stg_u32_sc(unsigned* p, unsigned v) {
  asm volatile("global_store_dword %0, %1, off sc0 sc1" :: "v"(p), "v"(v) : "memory");
}

// ---------------------------------------------------------------------------
// prep: pack weights + h0 initial replicas (INIT_H) + zero bar region.
// WA slot ((cg*4+g)*96+kc)*64+l holds W_g[j=cg*16+(l&15)][kc*32+8*(l>>4)+e]
// WB slot ((cg*4+v)*8+kc)*64+l holds Wo[j][2048 + v*256+kc*32+8*(l>>4)+e].
// h/c slice tile: u32 idx (grp*64+cg)*128 + r16*8 + cpr = pair (2 bf16).
// ---------------------------------------------------------------------------
#define Z0 1310720LL
#define Z1 131072LL
#define Z2 32768LL
#define Z3 32768LL

__global__ __launch_bounds__(256)
void prep_kernel(const float* __restrict__ h0, const float* __restrict__ c0,
                 const float* __restrict__ Ww, const float* __restrict__ Wf,
                 const float* __restrict__ Wc, const float* __restrict__ Wo,
                 char* __restrict__ ws) {
  __hip_bfloat16* WA  = (__hip_bfloat16*)ws;
  __hip_bfloat16* WB  = (__hip_bfloat16*)(ws + OFF_WB);
  unsigned*      initH = (unsigned*)(ws + INIT_H);
  unsigned*       bar = (unsigned*)(ws + OFF_BAR);

  const long long total = Z0 + Z1 + Z2 + Z3;
  for (long long idx = (long long)blockIdx.x * 256 + threadIdx.x; idx < total;
       idx += (long long)gridDim.x * 256) {
    if (idx < Z0) {
      int l  = (int)(idx & 63);
      int s  = (int)((idx >> 6) % 320);
      int cg = (int)(idx / (320 * 64));
      int g, kc;
      if (s < 96)       { g = 0; kc = s; }
      else if (s < 192) { g = 1; kc = s - 96; }
      else if (s < 256) { g = 2; kc = s - 192; }
      else              { g = 3; kc = s - 256; }
      int j  = cg * 16 + (l & 15);
      int kb = kc * 32 + ((l >> 4) << 3);
      const float* W; int rl;
      if (g == 0)      { W = Ww; rl = 3072; }
      else if (g == 1) { W = Wf; rl = 3072; }
      else if (g == 2) { W = Wc; rl = 2048; }
      else             { W = Wo; rl = 3072; }
      const float* src = W + (size_t)j * rl + kb;
      __hip_bfloat16* dst = WA + ((((size_t)cg * 4 + g) * 96 + kc) * 64 + l) * 8;
#pragma unroll
      for (int e = 0; e < 8; ++e) dst[e] = __float2bfloat16(src[e]);
    } else if (idx < Z0 + Z1) {
      long long q = idx - Z0;
      int l  = (int)(q & 63);
      int kc = (int)((q >> 6) & 7);
      int v  = (int)((q >> 9) & 3);
      int cg = (int)(q >> 11);
      int j  = cg * 16 + (l & 15);
      int k  = 2048 + v * 256 + kc * 32 + ((l >> 4) << 3);
      const float* src = Wo + (size_t)j * 3072 + k;
      __hip_bfloat16* dst = WB + ((((size_t)cg * 4 + v) * 8 + kc) * 64 + l) * 8;
#pragma unroll
      for (int e = 0; e < 8; ++e) dst[e] = __float2bfloat16(src[e]);
    } else if (idx < Z0 + Z1 + Z2) {
      int u  = (int)(idx - (Z0 + Z1));        // pair index: R=u>>9, pp=u&511
      int R  = u >> 9, pp = u & 511;
      int cgp = pp >> 3, cprp = pp & 7;
      int dst = ((R >> 4) * 64 + cgp) * 128 + (R & 15) * 8 + cprp;
      const float* hs = h0 + (size_t)R * 1024 + 2 * pp;
      unsigned pv = pk2(hs[0], hs[1]);
#pragma unroll
      for (int r = 0; r < 4; ++r) initH[r * 32768 + dst] = pv;
    } else {
      int i = (int)(idx - (Z0 + Z1 + Z2));
      bar[i] = 0u;                     // flags + ready counter
    }
  }
}

// ---------------------------------------------------------------------------
// main persistent kernel
// ---------------------------------------------------------------------------
__global__ __launch_bounds__(256, 1)
void lstm_kernel(const float* __restrict__ x,  const float* __restrict__ h0,
                 const float* __restrict__ c0,
                 const float* __restrict__ bw, const float* __restrict__ bfg,
                 const float* __restrict__ bc, const float* __restrict__ bo,
                 float* __restrict__ out, char* __restrict__ ws) {
  (void)h0;
  char*     repH  = ws + REP_H;
  char*     repC  = ws + REP_C;
  char*     initH = ws + INIT_H;
  unsigned* bar   = (unsigned*)(ws + OFF_BAR);
  unsigned* hflag = bar;                 // + r*4096 + (grp*64+cg)*16
  unsigned* cflag = bar + 16384;         // same layout
  unsigned* ready = bar + 15;            // unused dword of flag slot 0

  const int tid  = threadIdx.x;
  const int l    = tid & 63;
  const int wv   = tid >> 6;                         // wave = K-quarter
  const int ks   = wv;
  const int b    = blockIdx.x;
  const int cg   = ((b & 7) << 3) | ((b >> 3) & 7);  // XCD-partitioned col-group
  const int grp  = b >> 6;                           // batch row-group (0..3)
  const int col  = l & 15;
  const int kg   = l >> 4;
  const int row16 = col;                             // A-frag row within tile
  const int srow  = row16 & 7;                       // LDS swizzle key
  const int myrep = cg & 3;                          // consumer replica choice

  // per-gate weight base (this block's 16 columns): gate g at +g*96*64 slots
  const short8* BWb = (const short8*)ws + ((size_t)cg * 4) * 96 * 64 + l;
  const short8* BO  = (const short8*)(ws + OFF_WB) + ((size_t)(cg * 4 + wv)) * 8 * 64 + l;

  __shared__ __align__(16) char sx[32768];   // x tile  [16][1024] bf16, swizzled
  __shared__ __align__(16) char sc_[32768];  // c tile (carried across steps)
  __shared__ float lds[20][16][17];          // [ks*4+g] A-partials | [16+ks] B

  // combine mapping: tid<128 owns (crow, 2 cols)
  const int crow = tid >> 3;
  const int cpr  = tid & 7;
  const int coff = ((grp * 16 + crow) << 10) + (cg << 4) + 2 * cpr;
  float c_reg0 = 0.f, c_reg1 = 0.f;
  float bw0r = 0.f, bw1r = 0.f, bf0r = 0.f, bf1r = 0.f;
  float bc0r = 0.f, bc1r = 0.f, bo0r = 0.f, bo1r = 0.f;
  if (tid < 128) {
    c_reg0 = c0[coff]; c_reg1 = c0[coff + 1];
    int jc = (cg << 4) + 2 * cpr;
    bw0r = bw[jc];  bw1r = bw[jc + 1];
    bf0r = bfg[jc]; bf1r = bfg[jc + 1];
    bc0r = bc[jc];  bc1r = bc[jc + 1];
    bo0r = bo[jc];  bo1r = bo[jc + 1];
  }
  // producer tile offset within a slot (slice-grouped 512B tiles)
  const size_t tileoff = (size_t)(grp * 64 + cg) * 512 + crow * 32 + cpr * 4;
  const int flagoff = (grp * 64 + cg) * 16;

  // ---- startup: stage c0 tile fp32->bf16 -> swizzled sc_ (R13 math) ----
  {
    const float* cs = c0 + (size_t)grp * 16384;
#pragma unroll
    for (int i = 0; i < 8; ++i) {
      int q = i * 256 + tid;
      const float* s = cs + q * 8;
      float4 f0 = *(const float4*)s;
      float4 f1 = *(const float4*)(s + 4);
      short8 v;
      v[0] = bfc(f0.x); v[1] = bfc(f0.y); v[2] = bfc(f0.z); v[3] = bfc(f0.w);
      v[4] = bfc(f1.x); v[5] = bfc(f1.y); v[6] = bfc(f1.z); v[7] = bfc(f1.w);
      int rw = q >> 7, kb = (q & 127) ^ (rw & 7);
      *(short8*)(sc_ + rw * 2048 + (kb << 4)) = v;
    }
  }
  // ---- startup: stage x(0) tile (consumed by xA at t=0) ----
  {
    const float* xs = x + (size_t)grp * 16384;
#pragma unroll
    for (int i = 0; i < 8; ++i) {
      int q = i * 256 + tid;
      const float* s = xs + q * 8;
      float4 f0 = *(const float4*)s;
      float4 f1 = *(const float4*)(s + 4);
      short8 v;
      v[0] = bfc(f0.x); v[1] = bfc(f0.y); v[2] = bfc(f0.z); v[3] = bfc(f0.w);
      v[4] = bfc(f1.x); v[5] = bfc(f1.y); v[6] = bfc(f1.z); v[7] = bfc(f1.w);
      int rw = q >> 7, kb = (q & 127) ^ (rw & 7);
      *(short8*)(sx + rw * 2048 + (kb << 4)) = v;
    }
  }

  // ---- pin ALL loop-invariant weights in registers (R21-verified) ----
  short8 WX[4][8];
#pragma unroll
  for (int g = 0; g < 4; ++g)
#pragma unroll
    for (int q = 0; q < 8; ++q)
      WX[g][q] = BWb[(size_t)(g * 96 + ks * 8 + q) * 64];
  short8 WC[2][8];
#pragma unroll
  for (int g = 0; g < 2; ++g)
#pragma unroll
    for (int q = 0; q < 8; ++q)
      WC[g][q] = BWb[(size_t)(g * 96 + 64 + ks * 8 + q) * 64];
  short8 WH[4][8];
#pragma unroll
  for (int g = 0; g < 4; ++g)
#pragma unroll
    for (int q = 0; q < 8; ++q)
      WH[g][q] = BWb[(size_t)(g * 96 + 32 + ks * 8 + q) * 64];
  short8 WBo[8];
#pragma unroll
  for (int k = 0; k < 8; ++k) WBo[k] = BO[(size_t)k * 64];

  // ---- grid READY barrier: all weight-pin loads complete before any block
  //      may store into the WA-tail replica region (first such store: t=0 c).
  asm volatile("s_waitcnt vmcnt(0)" ::: "memory");
  __builtin_amdgcn_sched_barrier(0);
  __syncthreads();
  if (tid == 0) {
    __hip_atomic_fetch_add(ready, 1u, __ATOMIC_RELAXED, __HIP_MEMORY_SCOPE_AGENT);
    unsigned spins = 0;
    for (;;) {
      unsigned v = poll_sc(ready);
      if (v >= 256u) break;
      __builtin_amdgcn_s_sleep(1);
      if (++spins > (1u << 18)) break;               // failsafe: fail loud
    }
  }
  __syncthreads();                     // also covers startup sx/sc_ staging

  for (int t = 0; t < 512; ++t) {
    const int p = t & 1;
    // h(t-1) lives in slot p (t=0: prep-written INIT_H replicas)
    const char* hslot = (t == 0)
        ? (initH + (size_t)myrep * 131072 + (size_t)grp * 32768)
        : (repH + (size_t)(myrep * 2 + p) * 131072 + (size_t)grp * 32768);
    const char* cslotR = repC + (size_t)(myrep * 2 + (p ^ 1)) * 131072 +
                         (size_t)grp * 32768;

    // loop-top barrier: orders prev-step o-combine partial reads, sx gap
    // writes, sc_ carry writes vs this step's partial writes / LDS reads.
    __syncthreads();

    f32x4 acc[4][2];
#pragma unroll
    for (int g = 0; g < 4; ++g) {
      acc[g][0] = (f32x4){0.f, 0.f, 0.f, 0.f};
      acc[g][1] = (f32x4){0.f, 0.f, 0.f, 0.f};
    }

    // ---- phase A, x part: A-frag loaded once, reused by 4 gates (pinned W) ----
#pragma unroll
    for (int q = 0; q < 8; ++q) {
      int f = ks * 8 + q;
      short8 a = *(const short8*)(sx + row16 * 2048 + ((((f << 2) + kg) ^ srow) << 4));
      acc[0][q & 1] = __builtin_amdgcn_mfma_f32_16x16x32_bf16(a, WX[0][q], acc[0][q & 1], 0, 0, 0);
      acc[1][q & 1] = __builtin_amdgcn_mfma_f32_16x16x32_bf16(a, WX[1][q], acc[1][q & 1], 0, 0, 0);
      acc[2][q & 1] = __builtin_amdgcn_mfma_f32_16x16x32_bf16(a, WX[2][q], acc[2][q & 1], 0, 0, 0);
      acc[3][q & 1] = __builtin_amdgcn_mfma_f32_16x16x32_bf16(a, WX[3][q], acc[3][q & 1], 0, 0, 0);
    }
    // ---- phase A, c part (gates w,f only) — sc_ carries c(t-1) (pinned W) ----
#pragma unroll
    for (int q = 0; q < 8; ++q) {
      int f = ks * 8 + q;
      short8 a = *(const short8*)(sc_ + row16 * 2048 + ((((f << 2) + kg) ^ srow) << 4));
      acc[0][q & 1] = __builtin_amdgcn_mfma_f32_16x16x32_bf16(a, WC[0][q], acc[0][q & 1], 0, 0, 0);
      acc[1][q & 1] = __builtin_amdgcn_mfma_f32_16x16x32_bf16(a, WC[1][q], acc[1][q & 1], 0, 0, 0);
    }

    // ---- WAVE-LOCAL h wait: lanes 0-15 poll 16 producers, OWN replica ----
    if (l < 16) {
      const unsigned* pf = hflag + myrep * 4096 + (grp * 64 + ks * 16 + l) * 16;
      const unsigned want = 2u * (unsigned)t;
      unsigned spins = 0;
      for (;;) {
        unsigned v = poll_sc(pf);
        if (__all((int)(v >= want))) break;
        __builtin_amdgcn_s_sleep(1);
        if (++spins > (1u << 18)) break;             // failsafe: fail loud
      }
    }
    __builtin_amdgcn_sched_barrier(0);

    // ---- h pull: 8 fragments direct L3 -> registers (replica-sharded) ----
    {
      const char* hb2 = hslot + row16 * 32 + (kg & 1) * 16;
      const int s0 = ks * 16 + (kg >> 1);
      uint4v ha[8];
#pragma unroll
      for (int q = 0; q < 8; ++q)
        ha[q] = ldg_sc(hb2 + (size_t)(s0 + 2 * q) * 512);
      asm volatile("s_waitcnt vmcnt(0)" ::: "memory");
      __builtin_amdgcn_sched_barrier(0);
      // ---- phase A, h part: 8 frags x 4 gates, register-pinned B ----
#pragma unroll
      for (int q = 0; q < 8; ++q) {
        short8 a = __builtin_bit_cast(short8, ha[q]);
        acc[0][q & 1] = __builtin_amdgcn_mfma_f32_16x16x32_bf16(a, WH[0][q], acc[0][q & 1], 0, 0, 0);
        acc[1][q & 1] = __builtin_amdgcn_mfma_f32_16x16x32_bf16(a, WH[1][q], acc[1][q & 1], 0, 0, 0);
        acc[2][q & 1] = __builtin_amdgcn_mfma_f32_16x16x32_bf16(a, WH[2][q], acc[2][q & 1], 0, 0, 0);
        acc[3][q & 1] = __builtin_amdgcn_mfma_f32_16x16x32_bf16(a, WH[3][q], acc[3][q & 1], 0, 0, 0);
      }
    }
    // ---- write gate partials (per K-quarter) ----
#pragma unroll
    for (int g = 0; g < 4; ++g)
#pragma unroll
      for (int i = 0; i < 4; ++i)
        lds[ks * 4 + g][kg * 4 + i][col] = acc[g][0][i] + acc[g][1][i];
    __syncthreads();                   // partials ready for combine

    // ---- c_new combine (tid<128); 4-replica store; drain; 4 flag bumps ----
    if (tid < 128) {
      int c0i = 2 * cpr, c1i = 2 * cpr + 1;
      float aw0 = bw0r, aw1 = bw1r, af0 = bf0r, af1 = bf1r, ag0 = bc0r, ag1 = bc1r;
#pragma unroll
      for (int k = 0; k < 4; ++k) {
        aw0 += lds[k * 4 + 0][crow][c0i]; aw1 += lds[k * 4 + 0][crow][c1i];
        af0 += lds[k * 4 + 1][crow][c0i]; af1 += lds[k * 4 + 1][crow][c1i];
        ag0 += lds[k * 4 + 2][crow][c0i]; ag1 += lds[k * 4 + 2][crow][c1i];
      }
      float cn0 = sig_fast(af0) * c_reg0 + sig_fast(aw0) * tanh_fast(ag0);
      float cn1 = sig_fast(af1) * c_reg1 + sig_fast(aw1) * tanh_fast(ag1);
      c_reg0 = cn0; c_reg1 = cn1;
      unsigned pkv = pk2(cn0, cn1);
#pragma unroll
      for (int r = 0; r < 4; ++r)
        stg_u32_sc((unsigned*)(repC + (size_t)(r * 2 + (p ^ 1)) * 131072 + tileoff), pkv);
      asm volatile("s_waitcnt vmcnt(0)" ::: "memory");   // all replicas at L3
      if (l == 0) {
#pragma unroll
        for (int r = 0; r < 4; ++r)
          __hip_atomic_fetch_add(cflag + r * 4096 + flagoff, 1u,
                                 __ATOMIC_RELAXED, __HIP_MEMORY_SCOPE_AGENT);
      }
    }

    // ---- fill the c-exchange gap: stage x(t+1) (sx is dead here) ----
    if (t < 511) {
      const float* xs = x + (((size_t)t + 1) << 16) + (size_t)grp * 16384;
#pragma unroll
      for (int i = 0; i < 8; ++i) {
        int q = i * 256 + tid;
        const float* s = xs + q * 8;
        float4 f0 = *(const float4*)s;
        float4 f1 = *(const float4*)(s + 4);
        short8 v;
        v[0] = bfc(f0.x); v[1] = bfc(f0.y); v[2] = bfc(f0.z); v[3] = bfc(f0.w);
        v[4] = bfc(f1.x); v[5] = bfc(f1.y); v[6] = bfc(f1.z); v[7] = bfc(f1.w);
        int rw = q >> 7, kb = (q & 127) ^ (rw & 7);
        *(short8*)(sx + rw * 2048 + (kb << 4)) = v;
      }
    }

    // ---- WAVE-LOCAL c wait: lanes 0-15 poll 16 producers, OWN replica ----
    if (l < 16) {
      const unsigned* pf = cflag + myrep * 4096 + (grp * 64 + wv * 16 + l) * 16;
      const unsigned want = 2u * ((unsigned)t + 1u);
      unsigned spins = 0;
      for (;;) {
        unsigned v = poll_sc(pf);
        if (__all((int)(v >= want))) break;
        __builtin_amdgcn_s_sleep(1);
        if (++spins > (1u << 18)) break;             // failsafe: fail loud
      }
    }
    __builtin_amdgcn_sched_barrier(0);

    // ---- phase B: replica-sharded c pull -> MFMA; carry into sc_ ----
    {
      const char* cslot = cslotR + row16 * 32 + (kg & 1) * 16;
      uint4v ca[8];
#pragma unroll
      for (int kcc = 0; kcc < 8; ++kcc) {
        int s = wv * 16 + kcc * 2 + (kg >> 1);
        ca[kcc] = ldg_sc(cslot + (size_t)s * 512);
      }
      asm volatile("s_waitcnt vmcnt(0)" ::: "memory");
      __builtin_amdgcn_sched_barrier(0);
      f32x4 a0 = {0.f, 0.f, 0.f, 0.f}, a1 = {0.f, 0.f, 0.f, 0.f};
#pragma unroll
      for (int kcc = 0; kcc < 8; ++kcc) {
        short8 a = __builtin_bit_cast(short8, ca[kcc]);
        if (kcc & 1) a1 = __builtin_amdgcn_mfma_f32_16x16x32_bf16(a, WBo[kcc], a1, 0, 0, 0);
        else         a0 = __builtin_amdgcn_mfma_f32_16x16x32_bf16(a, WBo[kcc], a0, 0, 0, 0);
      }
      // carry write: unit = wv*32 + kcc*4 + kg (verified bijection over tid)
      const int ub = wv * 32 + kg;
#pragma unroll
      for (int kcc = 0; kcc < 8; ++kcc)
        *(uint4v*)(sc_ + row16 * 2048 + (((ub + kcc * 4) ^ srow) << 4)) = ca[kcc];
#pragma unroll
      for (int i = 0; i < 4; ++i)
        lds[16 + wv][kg * 4 + i][col] = a0[i] + a1[i];
    }
    __syncthreads();                   // phase-B partials ready

    // ---- o combine, h_new; 4-replica store; drain; 4 bumps; out[] ----
    if (tid < 128) {
      int c0i = 2 * cpr, c1i = 2 * cpr + 1;
      float s0 = bo0r, s1 = bo1r;
#pragma unroll
      for (int k = 0; k < 4; ++k) {
        s0 += lds[k * 4 + 3][crow][c0i] + lds[16 + k][crow][c0i];
        s1 += lds[k * 4 + 3][crow][c1i] + lds[16 + k][crow][c1i];
      }
      float o0 = sig_fast(s0), o1 = sig_fast(s1);
      float h0v = o0 * tanh_fast(c_reg0);
      float h1v = o1 * tanh_fast(c_reg1);
      unsigned pkv = pk2(h0v, h1v);
#pragma unroll
      for (int r = 0; r < 4; ++r)
        stg_u32_sc((unsigned*)(repH + (size_t)(r * 2 + (p ^ 1)) * 131072 + tileoff), pkv);
      asm volatile("s_waitcnt vmcnt(0)" ::: "memory");   // all replicas at L3
      if (l == 0) {
#pragma unroll
        for (int r = 0; r < 4; ++r)
          __hip_atomic_fetch_add(hflag + r * 4096 + flagoff, 1u,
                                 __ATOMIC_RELAXED, __HIP_MEMORY_SCOPE_AGENT);
      }
      float2 hv; hv.x = h0v; hv.y = h1v;
      *(float2*)(out + ((size_t)t << 16) + coff) = hv;
      if (t == 511) {                    // finals: owner writes directly
        *(float2*)(out + ((size_t)512 << 16) + coff) = hv;
        float2 cv; cv.x = c_reg0; cv.y = c_reg1;
        *(float2*)(out + ((size_t)512 << 16) + 65536 + coff) = cv;
      }
    }
  }
}

extern "C" void kernel_launch(void* const* d_in, const int* in_sizes, int n_in,
                              void* d_out, int out_size, void* d_ws, size_t ws_size,
                              hipStream_t stream) {
  (void)in_sizes; (void)n_in; (void)out_size;
  const float* x  = (const float*)d_in[0];
  const float* h0 = (const float*)d_in[1];
  const float* c0 = (const float*)d_in[2];
  const float* Ww = (const float*)d_in[3];
  const float* bw = (const float*)d_in[4];
  const float* Wf = (const float*)d_in[5];
  const float* bfg= (const float*)d_in[6];
  const float* Wc = (const float*)d_in[7];
  const float* bc = (const float*)d_in[8];
  const float* Wo = (const float*)d_in[9];
  const float* bo = (const float*)d_in[10];

  if (ws_size < (size_t)WS_NEED) return;  // leaves poison -> loud failure

  prep_kernel<<<dim3(2048), dim3(256), 0, stream>>>(h0, c0, Ww, Wf, Wc, Wo,
                                                    (char*)d_ws);
  lstm_kernel<<<dim3(256), dim3(256), 0, stream>>>(x, h0, c0, bw, bfg, bc, bo,
                                                   (float*)d_out, (char*)d_ws);
}

// Round 15
// 4073.896 us; speedup vs baseline: 1.0495x; 1.0495x over previous
//
#include <hip/hip_runtime.h>
#include <hip/hip_bf16.h>
#include <stdint.h>

// ---------------------------------------------------------------------------
// Peephole LSTM, SEQ=512, B=64, I=H=1024.  Persistent-kernel, 256 blocks.
// Round-24: REVERT to R21 (best verified: 4.108ms).  R22 (hoisted probes,
// +4%) and R23 (4x replication, +4%) both refuted their theories; the
// two-all-gather-per-step chain at minimal protocol + minimal traffic IS
// the structure's floor.  Locking the best kernel back in.
//
// Cumulative verified structure (R12/R14/R16/R18/R19/R21):
//  * 256 blocks x 256 thr (1/CU, 1 wave/SIMD -> 512-VGPR budget).
//  * ALL loop-invariant weights register-pinned (WX/WC/WH/WBo, 88 frags):
//    zero steady-state weight streaming (R21: -49MB/step L3 traffic, +44%).
//  * K-split phase A: wave = K-quarter, computes all 4 gates; A-fragments
//    (sx/sc_) loaded once, reused 4x; h pulled direct L3->registers
//    (no LDS staging); wave-local gating (16 producers, max-of-16).
//  * Slice-grouped h/c payloads (512B/producer tile), 2-slot rings.
//  * Wave-autonomous arrives: producer waves drain OWN stores, bump flags
//    (atomic +1; 2 bumps/step -> consumer wants 2t / 2(t+1)).
//  * sc_ carries c(t-1) block-locally (phase-B carry write, bijection
//    unit = wv*32 + kcc*4 + kg); x(t+1) staged in the c-exchange gap.
//  * All cross-block comm sc0 sc1 (L3-coherent; sc0-only is L1-stale, R20).
// ---------------------------------------------------------------------------

typedef __attribute__((ext_vector_type(8))) short short8;
typedef __attribute__((ext_vector_type(4))) float f32x4;
typedef __attribute__((ext_vector_type(4))) unsigned int uint4v;

#define OFF_WB   25165824u   // WA: 64cg*4g*96kc*64l*8e bf16
#define OFF_HBF  27262976u   // WB: 2097152
#define OFF_CBF  27525120u   // hbf: 2 slots * 131072 (slice-grouped)
#define OFF_BAR  27787264u   // cbf: 2 slots * 131072 (slice-grouped)
#define WS_NEED  27918336u   // bar: hflag @0, cflag @ +4096 dwords

__device__ __forceinline__ short bfc(float f) {
  __hip_bfloat16 h = __float2bfloat16(f);
  return *reinterpret_cast<short*>(&h);
}
__device__ __forceinline__ unsigned pk2(float a, float b) {
  __hip_bfloat16 ha = __float2bfloat16(a), hb = __float2bfloat16(b);
  unsigned short ua = *reinterpret_cast<unsigned short*>(&ha);
  unsigned short ub = *reinterpret_cast<unsigned short*>(&hb);
  return (unsigned)ua | ((unsigned)ub << 16);
}
__device__ __forceinline__ float sig_fast(float v) {
  return __fdividef(1.f, 1.f + __expf(-v));
}
__device__ __forceinline__ float tanh_fast(float v) {
  float a = fabsf(v);
  float e = __expf(-2.f * a);
  float t = (1.f - e) * __fdividef(1.f, 1.f + e);
  return copysignf(t, v);
}

// ---- L1+L2-bypassing accesses (coherent at L3 across XCDs) ----
__device__ __forceinline__ uint4v ldg_sc(const void* p) {
  uint4v r;
  asm volatile("global_load_dwordx4 %0, %1, off sc0 sc1" : "=v"(r) : "v"(p));
  return r;
}
__device__ __forceinline__ unsigned poll_sc(const unsigned* p) {
  unsigned r;
  asm volatile("global_load_dword %0, %1, off sc0 sc1\n\ts_waitcnt vmcnt(0)"
               : "=v"(r) : "v"(p) : "memory");
  return r;
}
__device__ __forceinline__ void stg_u32_sc(unsigned* p, unsigned v) {
  asm volatile("global_store_dword %0, %1, off sc0 sc1" :: "v"(p), "v"(v) : "memory");
}

// ---------------------------------------------------------------------------
// prep: pack weights + slice-grouped h0 (slot 0) + zero bar region.
// WA slot ((cg*4+g)*96+kc)*64+l holds W_g[j=cg*16+(l&15)][kc*32+8*(l>>4)+e]
// WB slot ((cg*4+v)*8+kc)*64+l holds Wo[j][2048 + v*256+kc*32+8*(l>>4)+e].
// h slice tile: u32 idx ((grp*64+cg)*128 + r*8 + cpr) = pair (2 bf16).
// ---------------------------------------------------------------------------
#define Z0 1310720LL
#define Z1 131072LL
#define Z2 32768LL
#define Z3 32768LL

__global__ __launch_bounds__(256)
void prep_kernel(const float* __restrict__ h0, const float* __restrict__ c0,
                 const float* __restrict__ Ww, const float* __restrict__ Wf,
                 const float* __restrict__ Wc, const float* __restrict__ Wo,
                 char* __restrict__ ws) {
  __hip_bfloat16* WA  = (__hip_bfloat16*)ws;
  __hip_bfloat16* WB  = (__hip_bfloat16*)(ws + OFF_WB);
  unsigned*     hbf32 = (unsigned*)(ws + OFF_HBF);   // slot 0
  unsigned*       bar = (unsigned*)(ws + OFF_BAR);

  const long long total = Z0 + Z1 + Z2 + Z3;
  for (long long idx = (long long)blockIdx.x * 256 + threadIdx.x; idx < total;
       idx += (long long)gridDim.x * 256) {
    if (idx < Z0) {
      int l  = (int)(idx & 63);
      int s  = (int)((idx >> 6) % 320);
      int cg = (int)(idx / (320 * 64));
      int g, kc;
      if (s < 96)       { g = 0; kc = s; }
      else if (s < 192) { g = 1; kc = s - 96; }
      else if (s < 256) { g = 2; kc = s - 192; }
      else              { g = 3; kc = s - 256; }
      int j  = cg * 16 + (l & 15);
      int kb = kc * 32 + ((l >> 4) << 3);
      const float* W; int rl;
      if (g == 0)      { W = Ww; rl = 3072; }
      else if (g == 1) { W = Wf; rl = 3072; }
      else if (g == 2) { W = Wc; rl = 2048; }
      else             { W = Wo; rl = 3072; }
      const float* src = W + (size_t)j * rl + kb;
      __hip_bfloat16* dst = WA + ((((size_t)cg * 4 + g) * 96 + kc) * 64 + l) * 8;
#pragma unroll
      for (int e = 0; e < 8; ++e) dst[e] = __float2bfloat16(src[e]);
    } else if (idx < Z0 + Z1) {
      long long q = idx - Z0;
      int l  = (int)(q & 63);
      int kc = (int)((q >> 6) & 7);
      int v  = (int)((q >> 9) & 3);
      int cg = (int)(q >> 11);
      int j  = cg * 16 + (l & 15);
      int k  = 2048 + v * 256 + kc * 32 + ((l >> 4) << 3);
      const float* src = Wo + (size_t)j * 3072 + k;
      __hip_bfloat16* dst = WB + ((((size_t)cg * 4 + v) * 8 + kc) * 64 + l) * 8;
#pragma unroll
      for (int e = 0; e < 8; ++e) dst[e] = __float2bfloat16(src[e]);
    } else if (idx < Z0 + Z1 + Z2) {
      int u  = (int)(idx - (Z0 + Z1));        // pair index: R=u>>9, pp=u&511
      int R  = u >> 9, pp = u & 511;
      int cgp = pp >> 3, cprp = pp & 7;
      int dst = ((R >> 4) * 64 + cgp) * 128 + (R & 15) * 8 + cprp;
      const float* hs = h0 + (size_t)R * 1024 + 2 * pp;
      hbf32[dst] = pk2(hs[0], hs[1]);
    } else {
      int i = (int)(idx - (Z0 + Z1 + Z2));
      bar[i] = 0u;
    }
  }
}

// ---------------------------------------------------------------------------
// main persistent kernel
// ---------------------------------------------------------------------------
__global__ __launch_bounds__(256, 1)
void lstm_kernel(const float* __restrict__ x,  const float* __restrict__ c0,
                 const float* __restrict__ bw, const float* __restrict__ bfg,
                 const float* __restrict__ bc, const float* __restrict__ bo,
                 float* __restrict__ out, char* __restrict__ ws) {
  char*     hbf   = ws + OFF_HBF;
  char*     cbf   = ws + OFF_CBF;
  unsigned* hflag = (unsigned*)(ws + OFF_BAR);          // (grp*64+cg)*16
  unsigned* cflag = (unsigned*)(ws + OFF_BAR) + 4096;   // (grp*64+cg)*16

  const int tid  = threadIdx.x;
  const int l    = tid & 63;
  const int wv   = tid >> 6;                         // wave = K-quarter
  const int ks   = wv;
  const int b    = blockIdx.x;
  const int cg   = ((b & 7) << 3) | ((b >> 3) & 7);  // XCD-partitioned col-group
  const int grp  = b >> 6;                           // batch row-group (0..3)
  const int col  = l & 15;
  const int kg   = l >> 4;
  const int row16 = col;                             // A-frag row within tile
  const int srow  = row16 & 7;                       // LDS swizzle key

  // per-gate weight base (this block's 16 columns): gate g at +g*96*64 slots
  const short8* BWb = (const short8*)ws + ((size_t)cg * 4) * 96 * 64 + l;
  const short8* BO  = (const short8*)(ws + OFF_WB) + ((size_t)(cg * 4 + wv)) * 8 * 64 + l;

  __shared__ __align__(16) char sx[32768];   // x tile  [16][1024] bf16, swizzled
  __shared__ __align__(16) char sc_[32768];  // c tile (carried across steps)
  __shared__ float lds[20][16][17];          // [ks*4+g] A-partials | [16+ks] B

  // combine mapping: tid<128 owns (crow, 2 cols)
  const int crow = tid >> 3;
  const int cpr  = tid & 7;
  const int coff = ((grp * 16 + crow) << 10) + (cg << 4) + 2 * cpr;
  float c_reg0 = 0.f, c_reg1 = 0.f;
  float bw0r = 0.f, bw1r = 0.f, bf0r = 0.f, bf1r = 0.f;
  float bc0r = 0.f, bc1r = 0.f, bo0r = 0.f, bo1r = 0.f;
  if (tid < 128) {
    c_reg0 = c0[coff]; c_reg1 = c0[coff + 1];
    int jc = (cg << 4) + 2 * cpr;
    bw0r = bw[jc];  bw1r = bw[jc + 1];
    bf0r = bfg[jc]; bf1r = bfg[jc + 1];
    bc0r = bc[jc];  bc1r = bc[jc + 1];
    bo0r = bo[jc];  bo1r = bo[jc + 1];
  }
  // producer targets (slice-grouped 512B tiles)
  char* hDst = hbf + ((size_t)(grp * 64 + cg)) * 512 + crow * 32 + cpr * 4;
  char* cDst = cbf + ((size_t)(grp * 64 + cg)) * 512 + crow * 32 + cpr * 4;
  unsigned* hflagP = hflag + (grp * 64 + cg) * 16;
  unsigned* cflagP = cflag + (grp * 64 + cg) * 16;

  // ---- startup: stage c0 tile fp32->bf16 -> swizzled sc_ (R13 math) ----
  {
    const float* cs = c0 + (size_t)grp * 16384;
#pragma unroll
    for (int i = 0; i < 8; ++i) {
      int q = i * 256 + tid;
      const float* s = cs + q * 8;
      float4 f0 = *(const float4*)s;
      float4 f1 = *(const float4*)(s + 4);
      short8 v;
      v[0] = bfc(f0.x); v[1] = bfc(f0.y); v[2] = bfc(f0.z); v[3] = bfc(f0.w);
      v[4] = bfc(f1.x); v[5] = bfc(f1.y); v[6] = bfc(f1.z); v[7] = bfc(f1.w);
      int rw = q >> 7, kb = (q & 127) ^ (rw & 7);
      *(short8*)(sc_ + rw * 2048 + (kb << 4)) = v;
    }
  }
  // ---- startup: stage x(0) tile (consumed by xA at t=0) ----
  {
    const float* xs = x + (size_t)grp * 16384;
#pragma unroll
    for (int i = 0; i < 8; ++i) {
      int q = i * 256 + tid;
      const float* s = xs + q * 8;
      float4 f0 = *(const float4*)s;
      float4 f1 = *(const float4*)(s + 4);
      short8 v;
      v[0] = bfc(f0.x); v[1] = bfc(f0.y); v[2] = bfc(f0.z); v[3] = bfc(f0.w);
      v[4] = bfc(f1.x); v[5] = bfc(f1.y); v[6] = bfc(f1.z); v[7] = bfc(f1.w);
      int rw = q >> 7, kb = (q & 127) ^ (rw & 7);
      *(short8*)(sx + rw * 2048 + (kb << 4)) = v;
    }
  }

  // ---- pin ALL loop-invariant weights in registers:
  //      WX[4][8] x-part, WC[2][8] c-part, WH[4][8] h-part, WBo[8] phase-B.
  //      88 frags = 352 VGPR; total ~430 < 512 budget at 1 wave/SIMD. ----
  short8 WX[4][8];
#pragma unroll
  for (int g = 0; g < 4; ++g)
#pragma unroll
    for (int q = 0; q < 8; ++q)
      WX[g][q] = BWb[(size_t)(g * 96 + ks * 8 + q) * 64];
  short8 WC[2][8];
#pragma unroll
  for (int g = 0; g < 2; ++g)
#pragma unroll
    for (int q = 0; q < 8; ++q)
      WC[g][q] = BWb[(size_t)(g * 96 + 64 + ks * 8 + q) * 64];
  short8 WH[4][8];
#pragma unroll
  for (int g = 0; g < 4; ++g)
#pragma unroll
    for (int q = 0; q < 8; ++q)
      WH[g][q] = BWb[(size_t)(g * 96 + 32 + ks * 8 + q) * 64];
  short8 WBo[8];
#pragma unroll
  for (int k = 0; k < 8; ++k) WBo[k] = BO[(size_t)k * 64];

  __syncthreads();                     // startup sx/sc_ visible block-wide

  for (int t = 0; t < 512; ++t) {
    const int p = t & 1;
    const char* hslot = hbf + (size_t)p * 131072 + (size_t)grp * 32768;
    char* cslotW = cbf + (size_t)(p ^ 1) * 131072;   // c_new slot this step

    // loop-top barrier: orders prev-step o-combine partial reads, sx gap
    // writes, sc_ carry writes vs this step's partial writes / LDS reads.
    __syncthreads();

    f32x4 acc[4][2];
#pragma unroll
    for (int g = 0; g < 4; ++g) {
      acc[g][0] = (f32x4){0.f, 0.f, 0.f, 0.f};
      acc[g][1] = (f32x4){0.f, 0.f, 0.f, 0.f};
    }

    // ---- phase A, x part: A-frag loaded once, reused by 4 gates (pinned W) ----
#pragma unroll
    for (int q = 0; q < 8; ++q) {
      int f = ks * 8 + q;
      short8 a = *(const short8*)(sx + row16 * 2048 + ((((f << 2) + kg) ^ srow) << 4));
      acc[0][q & 1] = __builtin_amdgcn_mfma_f32_16x16x32_bf16(a, WX[0][q], acc[0][q & 1], 0, 0, 0);
      acc[1][q & 1] = __builtin_amdgcn_mfma_f32_16x16x32_bf16(a, WX[1][q], acc[1][q & 1], 0, 0, 0);
      acc[2][q & 1] = __builtin_amdgcn_mfma_f32_16x16x32_bf16(a, WX[2][q], acc[2][q & 1], 0, 0, 0);
      acc[3][q & 1] = __builtin_amdgcn_mfma_f32_16x16x32_bf16(a, WX[3][q], acc[3][q & 1], 0, 0, 0);
    }
    // ---- phase A, c part (gates w,f only) — sc_ carries c(t-1) (pinned W) ----
#pragma unroll
    for (int q = 0; q < 8; ++q) {
      int f = ks * 8 + q;
      short8 a = *(const short8*)(sc_ + row16 * 2048 + ((((f << 2) + kg) ^ srow) << 4));
      acc[0][q & 1] = __builtin_amdgcn_mfma_f32_16x16x32_bf16(a, WC[0][q], acc[0][q & 1], 0, 0, 0);
      acc[1][q & 1] = __builtin_amdgcn_mfma_f32_16x16x32_bf16(a, WC[1][q], acc[1][q & 1], 0, 0, 0);
    }

    // ---- WAVE-LOCAL h wait: lanes 0-15 poll this quarter's 16 producers ----
    if (l < 16) {
      const unsigned* pf = hflag + (grp * 64 + ks * 16 + l) * 16;
      const unsigned want = 2u * (unsigned)t;
      unsigned spins = 0;
      for (;;) {
        unsigned v = poll_sc(pf);
        if (__all((int)(v >= want))) break;
        __builtin_amdgcn_s_sleep(1);
        if (++spins > (1u << 18)) break;             // failsafe: fail loud
      }
    }
    __builtin_amdgcn_sched_barrier(0);

    // ---- h pull: 8 fragments direct L3 -> registers (slice-grouped) ----
    {
      const char* hb2 = hslot + row16 * 32 + (kg & 1) * 16;
      const int s0 = ks * 16 + (kg >> 1);
      uint4v ha[8];
#pragma unroll
      for (int q = 0; q < 8; ++q)
        ha[q] = ldg_sc(hb2 + (size_t)(s0 + 2 * q) * 512);
      asm volatile("s_waitcnt vmcnt(0)" ::: "memory");
      __builtin_amdgcn_sched_barrier(0);
      // ---- phase A, h part: 8 frags x 4 gates, register-pinned B ----
#pragma unroll
      for (int q = 0; q < 8; ++q) {
        short8 a = __builtin_bit_cast(short8, ha[q]);
        acc[0][q & 1] = __builtin_amdgcn_mfma_f32_16x16x32_bf16(a, WH[0][q], acc[0][q & 1], 0, 0, 0);
        acc[1][q & 1] = __builtin_amdgcn_mfma_f32_16x16x32_bf16(a, WH[1][q], acc[1][q & 1], 0, 0, 0);
        acc[2][q & 1] = __builtin_amdgcn_mfma_f32_16x16x32_bf16(a, WH[2][q], acc[2][q & 1], 0, 0, 0);
        acc[3][q & 1] = __builtin_amdgcn_mfma_f32_16x16x32_bf16(a, WH[3][q], acc[3][q & 1], 0, 0, 0);
      }
    }
    // ---- write gate partials (per K-quarter) ----
#pragma unroll
    for (int g = 0; g < 4; ++g)
#pragma unroll
      for (int i = 0; i < 4; ++i)
        lds[ks * 4 + g][kg * 4 + i][col] = acc[g][0][i] + acc[g][1][i];
    __syncthreads();                   // partials ready for combine

    // ---- c_new combine (tid<128); slice store; own-wave drain; bump ----
    if (tid < 128) {
      int c0i = 2 * cpr, c1i = 2 * cpr + 1;
      float aw0 = bw0r, aw1 = bw1r, af0 = bf0r, af1 = bf1r, ag0 = bc0r, ag1 = bc1r;
#pragma unroll
      for (int k = 0; k < 4; ++k) {
        aw0 += lds[k * 4 + 0][crow][c0i]; aw1 += lds[k * 4 + 0][crow][c1i];
        af0 += lds[k * 4 + 1][crow][c0i]; af1 += lds[k * 4 + 1][crow][c1i];
        ag0 += lds[k * 4 + 2][crow][c0i]; ag1 += lds[k * 4 + 2][crow][c1i];
      }
      float cn0 = sig_fast(af0) * c_reg0 + sig_fast(aw0) * tanh_fast(ag0);
      float cn1 = sig_fast(af1) * c_reg1 + sig_fast(aw1) * tanh_fast(ag1);
      c_reg0 = cn0; c_reg1 = cn1;
      stg_u32_sc((unsigned*)(cDst + (size_t)(p ^ 1) * 131072), pk2(cn0, cn1));
      asm volatile("s_waitcnt vmcnt(0)" ::: "memory");   // own wave's store at L3
      if (l == 0)
        __hip_atomic_fetch_add(cflagP, 1u,
                               __ATOMIC_RELAXED, __HIP_MEMORY_SCOPE_AGENT);
    }

    // ---- fill the c-exchange gap: stage x(t+1) (sx is dead here) ----
    if (t < 511) {
      const float* xs = x + (((size_t)t + 1) << 16) + (size_t)grp * 16384;
#pragma unroll
      for (int i = 0; i < 8; ++i) {
        int q = i * 256 + tid;
        const float* s = xs + q * 8;
        float4 f0 = *(const float4*)s;
        float4 f1 = *(const float4*)(s + 4);
        short8 v;
        v[0] = bfc(f0.x); v[1] = bfc(f0.y); v[2] = bfc(f0.z); v[3] = bfc(f0.w);
        v[4] = bfc(f1.x); v[5] = bfc(f1.y); v[6] = bfc(f1.z); v[7] = bfc(f1.w);
        int rw = q >> 7, kb = (q & 127) ^ (rw & 7);
        *(short8*)(sx + rw * 2048 + (kb << 4)) = v;
      }
    }

    // ---- WAVE-LOCAL c wait: lanes 0-15 poll this wave's 16 producers ----
    if (l < 16) {
      const unsigned* pf = cflag + (grp * 64 + wv * 16 + l) * 16;
      const unsigned want = 2u * ((unsigned)t + 1u);
      unsigned spins = 0;
      for (;;) {
        unsigned v = poll_sc(pf);
        if (__all((int)(v >= want))) break;
        __builtin_amdgcn_s_sleep(1);
        if (++spins > (1u << 18)) break;             // failsafe: fail loud
      }
    }
    __builtin_amdgcn_sched_barrier(0);

    // ---- phase B: slice-layout c pull (wave-local slices) -> MFMA; carry ----
    {
      const char* cslot = cslotW + (size_t)grp * 32768 + row16 * 32 + (kg & 1) * 16;
      uint4v ca[8];
#pragma unroll
      for (int kcc = 0; kcc < 8; ++kcc) {
        int s = wv * 16 + kcc * 2 + (kg >> 1);
        ca[kcc] = ldg_sc(cslot + (size_t)s * 512);
      }
      asm volatile("s_waitcnt vmcnt(0)" ::: "memory");
      __builtin_amdgcn_sched_barrier(0);
      f32x4 a0 = {0.f, 0.f, 0.f, 0.f}, a1 = {0.f, 0.f, 0.f, 0.f};
#pragma unroll
      for (int kcc = 0; kcc < 8; ++kcc) {
        short8 a = __builtin_bit_cast(short8, ca[kcc]);
        if (kcc & 1) a1 = __builtin_amdgcn_mfma_f32_16x16x32_bf16(a, WBo[kcc], a1, 0, 0, 0);
        else         a0 = __builtin_amdgcn_mfma_f32_16x16x32_bf16(a, WBo[kcc], a0, 0, 0, 0);
      }
      // carry write: unit = wv*32 + kcc*4 + kg (verified bijection over tid)
      const int ub = wv * 32 + kg;
#pragma unroll
      for (int kcc = 0; kcc < 8; ++kcc)
        *(uint4v*)(sc_ + row16 * 2048 + (((ub + kcc * 4) ^ srow) << 4)) = ca[kcc];
#pragma unroll
      for (int i = 0; i < 4; ++i)
        lds[16 + wv][kg * 4 + i][col] = a0[i] + a1[i];
    }
    __syncthreads();                   // phase-B partials ready

    // ---- o combine, h_new; slice store; own-wave drain; bump; out[] ----
    if (tid < 128) {
      int c0i = 2 * cpr, c1i = 2 * cpr + 1;
      float s0 = bo0r, s1 = bo1r;
#pragma unroll
      for (int k = 0; k < 4; ++k) {
        s0 += lds[k * 4 + 3][crow][c0i] + lds[16 + k][crow][c0i];
        s1 += lds[k * 4 + 3][crow][c1i] + lds[16 + k][crow][c1i];
      }
      float o0 = sig_fast(s0), o1 = sig_fast(s1);
      float h0v = o0 * tanh_fast(c_reg0);
      float h1v = o1 * tanh_fast(c_reg1);
      stg_u32_sc((unsigned*)(hDst + (size_t)(p ^ 1) * 131072), pk2(h0v, h1v));
      asm volatile("s_waitcnt vmcnt(0)" ::: "memory");   // own wave's h at L3
      if (l == 0)
        __hip_atomic_fetch_add(hflagP, 1u,
                               __ATOMIC_RELAXED, __HIP_MEMORY_SCOPE_AGENT);
      float2 hv; hv.x = h0v; hv.y = h1v;
      *(float2*)(out + ((size_t)t << 16) + coff) = hv;
      if (t == 511) {                    // finals: owner writes directly
        *(float2*)(out + ((size_t)512 << 16) + coff) = hv;
        float2 cv; cv.x = c_reg0; cv.y = c_reg1;
        *(float2*)(out + ((size_t)512 << 16) + 65536 + coff) = cv;
      }
    }
  }
}

extern "C" void kernel_launch(void* const* d_in, const int* in_sizes, int n_in,
                              void* d_out, int out_size, void* d_ws, size_t ws_size,
                              hipStream_t stream) {
  (void)in_sizes; (void)n_in; (void)out_size;
  const float* x  = (const float*)d_in[0];
  const float* h0 = (const float*)d_in[1];
  const float* c0 = (const float*)d_in[2];
  const float* Ww = (const float*)d_in[3];
  const float* bw = (const float*)d_in[4];
  const float* Wf = (const float*)d_in[5];
  const float* bfg= (const float*)d_in[6];
  const float* Wc = (const float*)d_in[7];
  const float* bc = (const float*)d_in[8];
  const float* Wo = (const float*)d_in[9];
  const float* bo = (const float*)d_in[10];

  if (ws_size < (size_t)WS_NEED) return;  // leaves poison -> loud failure

  prep_kernel<<<dim3(2048), dim3(256), 0, stream>>>(h0, c0, Ww, Wf, Wc, Wo,
                                                    (char*)d_ws);
  lstm_kernel<<<dim3(256), dim3(256), 0, stream>>>(x, c0, bw, bfg, bc, bo,
                                                   (float*)d_out, (char*)d_ws);
}